// Round 2
// baseline (599.842 us; speedup 1.0000x reference)
//
#include <hip/hip_runtime.h>

#define B_  4
#define S_  2048
#define D_  1024
#define H_  16
#define DK_ 64

typedef __attribute__((ext_vector_type(8))) __bf16 bf16x8;
typedef __attribute__((ext_vector_type(4))) float  f32x4;

#define AS1 __attribute__((address_space(1)))
#define AS3 __attribute__((address_space(3)))

// Async 16B global -> LDS. Per-lane dest must equal wave-uniform base + lane*16.
__device__ __forceinline__ void gl2lds16(const void* g, void* l) {
    __builtin_amdgcn_global_load_lds((const AS1 unsigned int*)g,
                                     (AS3 unsigned int*)l, 16, 0, 0);
}

__device__ __forceinline__ unsigned short f2bf(float f) {
    union { float f; unsigned u; } v; v.f = f;
    return (unsigned short)((v.u + 0x7FFFu + ((v.u >> 16) & 1u)) >> 16);
}

// pack bf16(f0) low | bf16(f1) high; round via +0x8000, v_perm pack.
__device__ __forceinline__ unsigned pk_bf16(float f0, float f1) {
    union { float f; unsigned u; } a, b; a.f = f0; b.f = f1;
    return __builtin_amdgcn_perm(b.u + 0x8000u, a.u + 0x8000u, 0x07060302u);
}

__device__ __forceinline__ void cast8(const float* __restrict__ x,
                                      unsigned short* __restrict__ y, int i) {
    float4 a = ((const float4*)x)[2 * i];
    float4 b = ((const float4*)x)[2 * i + 1];
    uint4 w;
    w.x = pk_bf16(a.x, a.y);
    w.y = pk_bf16(a.z, a.w);
    w.z = pk_bf16(b.x, b.y);
    w.w = pk_bf16(b.z, b.w);
    ((uint4*)y)[i] = w;
}

// Merged fp32->bf16 casts: grid.y selects tensor (activations q,k,v).
__global__ __launch_bounds__(256) void cast_act(
    const float* __restrict__ a, const float* __restrict__ b,
    const float* __restrict__ c, unsigned short* __restrict__ ya,
    unsigned short* __restrict__ yb, unsigned short* __restrict__ yc)
{
    const int sel = blockIdx.y;
    const float* x = (sel == 0) ? a : (sel == 1) ? b : c;
    unsigned short* y = (sel == 0) ? ya : (sel == 1) ? yb : yc;
    cast8(x, y, blockIdx.x * 256 + threadIdx.x);
}

// Merged weight casts: grid.y in 0..3.
__global__ __launch_bounds__(256) void cast_w(
    const float* __restrict__ a, const float* __restrict__ b,
    const float* __restrict__ c, const float* __restrict__ d,
    unsigned short* __restrict__ ya, unsigned short* __restrict__ yb,
    unsigned short* __restrict__ yc, unsigned short* __restrict__ yd)
{
    const int sel = blockIdx.y;
    const float* x = (sel == 0) ? a : (sel == 1) ? b : (sel == 2) ? c : d;
    unsigned short* y = (sel == 0) ? ya : (sel == 1) ? yb : (sel == 2) ? yc : yd;
    cast8(x, y, blockIdx.x * 256 + threadIdx.x);
}

// Fused QKV projection GEMM over N=3072 output cols (Wq;Wk;Wv rows contiguous).
// CRITICAL (R7/R8 bug): each projection has a DIFFERENT A-operand —
// Q = query@Wq, K = key@Wk, V = value@Wv. Selection is block-uniform:
// blockIdx.x 0..7 -> Q, 8..15 -> K, 16..23 -> V.
__global__ __launch_bounds__(256, 3) void gemm_qkv(
    const unsigned short* __restrict__ Xq, const unsigned short* __restrict__ Xk,
    const unsigned short* __restrict__ Xv, const unsigned short* __restrict__ Wqkv,
    const float* __restrict__ bq, const float* __restrict__ bk,
    const float* __restrict__ bv, unsigned short* __restrict__ Qw,
    unsigned short* __restrict__ Kw, unsigned short* __restrict__ Vt,
    float qscale)
{
    __shared__ unsigned short As[128 * 64];
    __shared__ unsigned short Bs[128 * 64];

    const int tid  = threadIdx.x;
    const int lane = tid & 63, wave = tid >> 6;
    const int l16  = lane & 15, quad = lane >> 4;
    const int wm = wave & 1, wn = wave >> 1;
    const int n0 = blockIdx.x * 128, m0 = blockIdx.y * 128;
    const int xr = l16 & 7;

    const int sel = blockIdx.x >> 3;               // 0=Q, 1=K, 2=V (block-uniform)
    const unsigned short* X = (sel == 0) ? Xq : (sel == 1) ? Xk : Xv;

    const int row8 = lane >> 3;
    const int sc   = ((lane & 7) ^ row8) * 8;

    f32x4 acc[4][4] = {};

    for (int k0 = 0; k0 < D_; k0 += 64) {
        __syncthreads();
        #pragma unroll
        for (int j = 0; j < 4; ++j) {
            const int ca = wave * 4 + j;
            const int r  = ca * 8 + row8;
            gl2lds16(X    + (size_t)(m0 + r) * D_ + k0 + sc, &As[ca * 512 + (lane & 63) * 8]);
            gl2lds16(Wqkv + (size_t)(n0 + r) * D_ + k0 + sc, &Bs[ca * 512 + (lane & 63) * 8]);
        }
        __syncthreads();

        #pragma unroll
        for (int s = 0; s < 2; ++s) {
            bf16x8 a[4], bb[4];
            #pragma unroll
            for (int i = 0; i < 4; ++i)
                a[i] = *(const bf16x8*)&As[(wm * 64 + i * 16 + l16) * 64 + (((s * 4 + quad) ^ xr)) * 8];
            #pragma unroll
            for (int j = 0; j < 4; ++j)
                bb[j] = *(const bf16x8*)&Bs[(wn * 64 + j * 16 + l16) * 64 + (((s * 4 + quad) ^ xr)) * 8];
            #pragma unroll
            for (int i = 0; i < 4; ++i)
                #pragma unroll
                for (int j = 0; j < 4; ++j)
                    acc[i][j] = __builtin_amdgcn_mfma_f32_16x16x32_bf16(a[i], bb[j], acc[i][j], 0, 0, 0);
        }
    }

    const int ncol = (blockIdx.x & 7) * 128 + wn * 64;   // col base within projection
    const float scale = (sel == 0) ? qscale : 1.0f;
    const float* bias = (sel == 0) ? bq : (sel == 1) ? bk : bv;

    if (sel == 2) {
        // V: transposed per-head write Vt[(b*D+dk)*S+s], packed b64 runs along s
        const int bb_ = m0 >> 11;
        #pragma unroll
        for (int j = 0; j < 4; ++j) {
            const int dk = ncol + j * 16 + l16;
            const float bvv = bias[dk];
            #pragma unroll
            for (int i = 0; i < 4; ++i) {
                const int sb = (m0 & (S_ - 1)) + wm * 64 + i * 16 + quad * 4;
                uint2 w;
                w.x = pk_bf16(acc[i][j][0] + bvv, acc[i][j][1] + bvv);
                w.y = pk_bf16(acc[i][j][2] + bvv, acc[i][j][3] + bvv);
                *(uint2*)(Vt + (size_t)(bb_ * D_ + dk) * S_ + sb) = w;
            }
        }
    } else {
        unsigned short* Outp = sel ? Kw : Qw;
        #pragma unroll
        for (int j = 0; j < 4; ++j) {
            const int n = ncol + j * 16 + l16;
            const float bvv = bias[n];
            #pragma unroll
            for (int i = 0; i < 4; ++i) {
                #pragma unroll
                for (int r = 0; r < 4; ++r) {
                    const int m = m0 + wm * 64 + i * 16 + quad * 4 + r;
                    Outp[(size_t)m * D_ + n] = f2bf((acc[i][j][r] + bvv) * scale);
                }
            }
        }
    }
}

// Output GEMM: C = X * W^T + bias (fp32 out), m97 pattern, 128x128 tile.
__global__ __launch_bounds__(256, 3) void gemm_out(
    const unsigned short* __restrict__ X, const unsigned short* __restrict__ W,
    const float* __restrict__ bias, float* __restrict__ Out)
{
    __shared__ unsigned short As[128 * 64];
    __shared__ unsigned short Bs[128 * 64];

    const int tid  = threadIdx.x;
    const int lane = tid & 63, wave = tid >> 6;
    const int l16  = lane & 15, quad = lane >> 4;
    const int wm = wave & 1, wn = wave >> 1;
    const int n0 = blockIdx.x * 128, m0 = blockIdx.y * 128;
    const int xr = l16 & 7;

    const int row8 = lane >> 3;
    const int sc   = ((lane & 7) ^ row8) * 8;

    f32x4 acc[4][4] = {};

    for (int k0 = 0; k0 < D_; k0 += 64) {
        __syncthreads();
        #pragma unroll
        for (int j = 0; j < 4; ++j) {
            const int ca = wave * 4 + j;
            const int r  = ca * 8 + row8;
            gl2lds16(X + (size_t)(m0 + r) * D_ + k0 + sc, &As[ca * 512 + (lane & 63) * 8]);
            gl2lds16(W + (size_t)(n0 + r) * D_ + k0 + sc, &Bs[ca * 512 + (lane & 63) * 8]);
        }
        __syncthreads();

        #pragma unroll
        for (int s = 0; s < 2; ++s) {
            bf16x8 a[4], bb[4];
            #pragma unroll
            for (int i = 0; i < 4; ++i)
                a[i] = *(const bf16x8*)&As[(wm * 64 + i * 16 + l16) * 64 + (((s * 4 + quad) ^ xr)) * 8];
            #pragma unroll
            for (int j = 0; j < 4; ++j)
                bb[j] = *(const bf16x8*)&Bs[(wn * 64 + j * 16 + l16) * 64 + (((s * 4 + quad) ^ xr)) * 8];
            #pragma unroll
            for (int i = 0; i < 4; ++i)
                #pragma unroll
                for (int j = 0; j < 4; ++j)
                    acc[i][j] = __builtin_amdgcn_mfma_f32_16x16x32_bf16(a[i], bb[j], acc[i][j], 0, 0, 0);
        }
    }

    #pragma unroll
    for (int j = 0; j < 4; ++j) {
        const int n = n0 + wn * 64 + j * 16 + l16;
        const float bv = bias[n];
        #pragma unroll
        for (int i = 0; i < 4; ++i) {
            #pragma unroll
            for (int r = 0; r < 4; ++r) {
                const int m = m0 + wm * 64 + i * 16 + quad * 4 + r;
                Out[(size_t)m * D_ + n] = acc[i][j][r] + bv;
            }
        }
    }
}

// Pack mask (B,S,S int32) into bitmask words: pm[(b*S+q)*(S/64)+w] bit k.
__global__ __launch_bounds__(256) void pack_mask(
    const int* __restrict__ mask, unsigned long long* __restrict__ pm)
{
    const int gid  = blockIdx.x * 256 + threadIdx.x;
    const int w    = gid >> 6;
    const int lane = threadIdx.x & 63;
    const int mv = mask[(size_t)w * 64 + lane];
    const unsigned long long bal = __ballot(mv != 0);
    if (lane == 0) pm[w] = bal;
}

// Flash attention, transposed-score, fixed-max softmax, MFMA row-sums.
// R2 (this round): K removed from LDS entirely — QK^T A-fragments load
// global->VGPR directly (lane (l16,quad) reads K[(k0+mb*16+l16)*D + h*64 +
// s*32 + quad*8]; the 4 quads of an l16 group cover one 64B line, L2-served).
// Kills the 4x-redundant 8KB/wave-tile Ks ds_reads (LDS reads -43%) and the
// K staging. K regs single-buffered: reload for kt+1 issues right after the
// QK^T MFMAs consume them (WAR order), covered by softmax+PV.
// LDS = 2*8K (V dbuf) + 8K (Ps) = 24576 B. VGPR ~90 (65-128 band, same
// 4 waves/SIMD as before — no occupancy change, pure work reduction).
__global__ __launch_bounds__(256, 4) void attn_kernel(
    const unsigned short* __restrict__ Q,
    const unsigned short* __restrict__ Kg,
    const unsigned short* __restrict__ Vt,
    const unsigned long long* __restrict__ pm,
    unsigned short* __restrict__ O)
{
    __shared__ unsigned short Vs[2][64 * 64];
    __shared__ unsigned short Ps[64 * 64];

    const int tid  = threadIdx.x;
    const int lane = tid & 63, wave = tid >> 6;
    const int l16  = lane & 15, quad = lane >> 4;
    const int bh = blockIdx.y, b = bh >> 4, h = bh & 15;
    const int q0 = blockIdx.x * 64;
    const int xq = l16 & 7;

    // all-ones B operand for the row-sum MFMA
    union { uint4 u; bf16x8 v; } ones_u;
    ones_u.u = make_uint4(0x3F803F80u, 0x3F803F80u, 0x3F803F80u, 0x3F803F80u);
    const bf16x8 vb_ones = ones_u.v;

    bf16x8 qa[2];
    {
        const unsigned short* qp =
            Q + (size_t)(b * S_ + q0 + wave * 16 + l16) * D_ + h * DK_ + quad * 8;
        qa[0] = *(const bf16x8*)qp;
        qa[1] = *(const bf16x8*)(qp + 32);
    }

    const unsigned short* Kbase = Kg + (size_t)(b * S_) * D_ + h * DK_;
    const unsigned short* Vbase = Vt + (size_t)(b * D_ + h * DK_) * S_;

    // K fragments in registers: ka[mb][s] covers K rows mb*16+l16 (A-frag:
    // row = l16 within block, contraction chunk = s*32 + quad*8).
    bf16x8 ka[4][2];
    const unsigned short* kp = Kbase + (size_t)l16 * D_ + quad * 8;
    auto loadK = [&](int k0) {
        #pragma unroll
        for (int mb = 0; mb < 4; ++mb) {
            const unsigned short* p = kp + (size_t)(k0 + mb * 16) * D_;
            ka[mb][0] = *(const bf16x8*)p;
            ka[mb][1] = *(const bf16x8*)(p + 32);
        }
    };

    // stage V tile kt into buffer bi (wave-uniform LDS base + lane*16)
    auto stage = [&](int bi2, int kt2) {
        const int k0 = kt2 * 64;
        #pragma unroll
        for (int j = 0; j < 2; ++j) {
            const int c = j * 256 + tid;
            const int row = c >> 3;
            const int cl = (c & 7) ^ (row & 7);
            gl2lds16(Vbase + (size_t)row * S_ + k0 + cl * 8, &Vs[bi2][c * 8]);
        }
    };

    const unsigned long long* pmq =
        pm + (size_t)(b * S_ + q0 + wave * 16 + l16) * (S_ / 64);

    f32x4 oacc[5] = {};

    loadK(0);
    stage(0, 0);
    __syncthreads();

    int bi = 0;
    for (int kt = 0; kt < S_ / 64; ++kt) {
        const unsigned long long wq = pmq[kt];
        const bool more = (kt + 1 < S_ / 64);
        if (more) stage(bi ^ 1, kt + 1);   // prefetch next V tile

        // S^T tile: rows k, cols q. A = K rows (registers), B = Q rows (regs).
        f32x4 sct[4] = {};
        __builtin_amdgcn_s_setprio(1);
        #pragma unroll
        for (int s = 0; s < 2; ++s) {
            #pragma unroll
            for (int mb = 0; mb < 4; ++mb)
                sct[mb] = __builtin_amdgcn_mfma_f32_16x16x32_bf16(ka[mb][s], qa[s], sct[mb], 0, 0, 0);
        }
        __builtin_amdgcn_s_setprio(0);

        // reload K regs for next tile (WAR on ka orders this after the MFMAs;
        // latency covered by softmax + PV below)
        if (more) loadK((kt + 1) * 64);

        #pragma unroll
        for (int mb = 0; mb < 4; ++mb) {
            const unsigned nib = (unsigned)(wq >> (mb * 16 + quad * 4)) & 0xFu;
            float e[4];
            #pragma unroll
            for (int r = 0; r < 4; ++r) {
                float x = __builtin_amdgcn_exp2f(sct[mb][r]);
                e[r] = ((nib >> r) & 1u) ? x : 0.f;
            }
            uint2 w;
            w.x = pk_bf16(e[0], e[1]);
            w.y = pk_bf16(e[2], e[3]);
            *(uint2*)&Ps[(wave * 16 + l16) * 64 + ((mb * 16 + quad * 4) ^ (xq * 8))] = w;
        }

        // PV (+ row-sum via constant ones B): A = P rows (q), B = Vs rows (d)
        __builtin_amdgcn_s_setprio(1);
        #pragma unroll
        for (int s = 0; s < 2; ++s) {
            bf16x8 pa = *(const bf16x8*)&Ps[(wave * 16 + l16) * 64 + ((s * 32 + quad * 8) ^ (xq * 8))];
            const int cs = ((s * 4 + quad) ^ xq) * 8;
            #pragma unroll
            for (int db = 0; db < 4; ++db) {
                bf16x8 vb = *(const bf16x8*)&Vs[bi][(db * 16 + l16) * 64 + cs];
                oacc[db] = __builtin_amdgcn_mfma_f32_16x16x32_bf16(pa, vb, oacc[db], 0, 0, 0);
            }
            oacc[4] = __builtin_amdgcn_mfma_f32_16x16x32_bf16(pa, vb_ones, oacc[4], 0, 0, 0);
        }
        __builtin_amdgcn_s_setprio(0);

        __syncthreads();   // drains prefetch vmcnt + guards V-buffer swap + Ps WAR
        bi ^= 1;
    }

    // epilogue: lane holds rows q = quad*4+r, cols d = db*16+l16; sum in oacc[4][r]
    #pragma unroll
    for (int r = 0; r < 4; ++r) {
        const float linv = 1.0f / oacc[4][r];
        const int qg = q0 + wave * 16 + quad * 4 + r;
        #pragma unroll
        for (int db = 0; db < 4; ++db) {
            O[(size_t)(b * S_ + qg) * D_ + h * DK_ + db * 16 + l16] =
                f2bf(oacc[db][r] * linv);
        }
    }
}

extern "C" void kernel_launch(void* const* d_in, const int* in_sizes, int n_in,
                              void* d_out, int out_size, void* d_ws, size_t ws_size,
                              hipStream_t stream)
{
    const float* q   = (const float*)d_in[0];
    const float* k   = (const float*)d_in[1];
    const float* v   = (const float*)d_in[2];
    const int* mask  = (const int*)d_in[3];
    const float* Wq  = (const float*)d_in[4];
    const float* bq  = (const float*)d_in[5];
    const float* Wk  = (const float*)d_in[6];
    const float* bk  = (const float*)d_in[7];
    const float* Wv  = (const float*)d_in[8];
    const float* bv  = (const float*)d_in[9];
    const float* Wo  = (const float*)d_in[10];
    const float* bo  = (const float*)d_in[11];

    const size_t MN = (size_t)B_ * S_ * D_;    // 8.4M elements
    const size_t WN = (size_t)D_ * D_;         // 1M elements
    unsigned short* qb  = (unsigned short*)d_ws;   // bf16 activations
    unsigned short* kb  = qb + MN;
    unsigned short* vb  = kb + MN;
    unsigned short* Qw  = vb + MN;
    unsigned short* Kw  = Qw + MN;
    unsigned short* Vt  = Kw + MN;
    unsigned short* wqb = Vt + MN;   // weights: wqb/wkb/wvb CONTIGUOUS = Wqkv
    unsigned short* wkb = wqb + WN;
    unsigned short* wvb = wkb + WN;
    unsigned short* wob = wvb + WN;
    unsigned short* Ow  = qb;   // qb dead after QKV-GEMM; attn writes Ow after
    // Packed mask (2 MB) in d_out scratch; final GEMM overwrites all of d_out.
    unsigned long long* pm = (unsigned long long*)d_out;

    dim3 blk(256);
    const int actBlocks = (int)(MN / 8 / 256);   // 4096
    const int wBlocks   = (int)(WN / 8 / 256);   // 512

    pack_mask<<<(B_ * S_ * S_) / 256, blk, 0, stream>>>(mask, pm);

    cast_act<<<dim3(actBlocks, 3), blk, 0, stream>>>(q, k, v, qb, kb, vb);
    cast_w<<<dim3(wBlocks, 4), blk, 0, stream>>>(Wq, Wk, Wv, Wo, wqb, wkb, wvb, wob);

    // Q scaled by log2(e)/sqrt(DK) -> attention scores already in exp2 domain
    const float qscale = 1.44269504088896341f * 0.125f;

    gemm_qkv<<<dim3(3 * D_ / 128, (B_ * S_) / 128), blk, 0, stream>>>(
        qb, kb, vb, wqb, bq, bk, bv, Qw, Kw, Vt, qscale);

    attn_kernel<<<dim3(S_ / 64, B_ * H_), blk, 0, stream>>>(Qw, Kw, Vt, pm, Ow);

    gemm_out<<<dim3(D_ / 128, (B_ * S_) / 128), blk, 0, stream>>>(
        Ow, wob, bo, (float*)d_out);
}

// Round 3
// 419.508 us; speedup vs baseline: 1.4299x; 1.4299x over previous
//
#include <hip/hip_runtime.h>

#define B_  4
#define S_  2048
#define D_  1024
#define H_  16
#define DK_ 64

typedef __attribute__((ext_vector_type(8))) __bf16 bf16x8;
typedef __attribute__((ext_vector_type(4))) float  f32x4;

#define AS1 __attribute__((address_space(1)))
#define AS3 __attribute__((address_space(3)))

// Async 16B global -> LDS. Per-lane dest must equal wave-uniform base + lane*16.
__device__ __forceinline__ void gl2lds16(const void* g, void* l) {
    __builtin_amdgcn_global_load_lds((const AS1 unsigned int*)g,
                                     (AS3 unsigned int*)l, 16, 0, 0);
}

__device__ __forceinline__ unsigned short f2bf(float f) {
    union { float f; unsigned u; } v; v.f = f;
    return (unsigned short)((v.u + 0x7FFFu + ((v.u >> 16) & 1u)) >> 16);
}

// pack bf16(f0) low | bf16(f1) high; round via +0x8000, v_perm pack.
__device__ __forceinline__ unsigned pk_bf16(float f0, float f1) {
    union { float f; unsigned u; } a, b; a.f = f0; b.f = f1;
    return __builtin_amdgcn_perm(b.u + 0x8000u, a.u + 0x8000u, 0x07060302u);
}

__device__ __forceinline__ void cast8(const float* __restrict__ x,
                                      unsigned short* __restrict__ y, int i) {
    float4 a = ((const float4*)x)[2 * i];
    float4 b = ((const float4*)x)[2 * i + 1];
    uint4 w;
    w.x = pk_bf16(a.x, a.y);
    w.y = pk_bf16(a.z, a.w);
    w.z = pk_bf16(b.x, b.y);
    w.w = pk_bf16(b.z, b.w);
    ((uint4*)y)[i] = w;
}

// Merged fp32->bf16 casts: grid.y selects tensor (activations q,k,v).
__global__ __launch_bounds__(256) void cast_act(
    const float* __restrict__ a, const float* __restrict__ b,
    const float* __restrict__ c, unsigned short* __restrict__ ya,
    unsigned short* __restrict__ yb, unsigned short* __restrict__ yc)
{
    const int sel = blockIdx.y;
    const float* x = (sel == 0) ? a : (sel == 1) ? b : c;
    unsigned short* y = (sel == 0) ? ya : (sel == 1) ? yb : yc;
    cast8(x, y, blockIdx.x * 256 + threadIdx.x);
}

// Merged weight casts: grid.y in 0..3.
__global__ __launch_bounds__(256) void cast_w(
    const float* __restrict__ a, const float* __restrict__ b,
    const float* __restrict__ c, const float* __restrict__ d,
    unsigned short* __restrict__ ya, unsigned short* __restrict__ yb,
    unsigned short* __restrict__ yc, unsigned short* __restrict__ yd)
{
    const int sel = blockIdx.y;
    const float* x = (sel == 0) ? a : (sel == 1) ? b : (sel == 2) ? c : d;
    unsigned short* y = (sel == 0) ? ya : (sel == 1) ? yb : (sel == 2) ? yc : yd;
    cast8(x, y, blockIdx.x * 256 + threadIdx.x);
}

// Fused QKV projection GEMM over N=3072 output cols (Wq;Wk;Wv rows contiguous).
// CRITICAL (R7/R8 bug): each projection has a DIFFERENT A-operand —
// Q = query@Wq, K = key@Wk, V = value@Wv. Selection is block-uniform:
// blockIdx.x 0..7 -> Q, 8..15 -> K, 16..23 -> V.
__global__ __launch_bounds__(256, 3) void gemm_qkv(
    const unsigned short* __restrict__ Xq, const unsigned short* __restrict__ Xk,
    const unsigned short* __restrict__ Xv, const unsigned short* __restrict__ Wqkv,
    const float* __restrict__ bq, const float* __restrict__ bk,
    const float* __restrict__ bv, unsigned short* __restrict__ Qw,
    unsigned short* __restrict__ Kw, unsigned short* __restrict__ Vt,
    float qscale)
{
    __shared__ unsigned short As[128 * 64];
    __shared__ unsigned short Bs[128 * 64];

    const int tid  = threadIdx.x;
    const int lane = tid & 63, wave = tid >> 6;
    const int l16  = lane & 15, quad = lane >> 4;
    const int wm = wave & 1, wn = wave >> 1;
    const int n0 = blockIdx.x * 128, m0 = blockIdx.y * 128;
    const int xr = l16 & 7;

    const int sel = blockIdx.x >> 3;               // 0=Q, 1=K, 2=V (block-uniform)
    const unsigned short* X = (sel == 0) ? Xq : (sel == 1) ? Xk : Xv;

    const int row8 = lane >> 3;
    const int sc   = ((lane & 7) ^ row8) * 8;

    f32x4 acc[4][4] = {};

    for (int k0 = 0; k0 < D_; k0 += 64) {
        __syncthreads();
        #pragma unroll
        for (int j = 0; j < 4; ++j) {
            const int ca = wave * 4 + j;
            const int r  = ca * 8 + row8;
            gl2lds16(X    + (size_t)(m0 + r) * D_ + k0 + sc, &As[ca * 512 + (lane & 63) * 8]);
            gl2lds16(Wqkv + (size_t)(n0 + r) * D_ + k0 + sc, &Bs[ca * 512 + (lane & 63) * 8]);
        }
        __syncthreads();

        #pragma unroll
        for (int s = 0; s < 2; ++s) {
            bf16x8 a[4], bb[4];
            #pragma unroll
            for (int i = 0; i < 4; ++i)
                a[i] = *(const bf16x8*)&As[(wm * 64 + i * 16 + l16) * 64 + (((s * 4 + quad) ^ xr)) * 8];
            #pragma unroll
            for (int j = 0; j < 4; ++j)
                bb[j] = *(const bf16x8*)&Bs[(wn * 64 + j * 16 + l16) * 64 + (((s * 4 + quad) ^ xr)) * 8];
            #pragma unroll
            for (int i = 0; i < 4; ++i)
                #pragma unroll
                for (int j = 0; j < 4; ++j)
                    acc[i][j] = __builtin_amdgcn_mfma_f32_16x16x32_bf16(a[i], bb[j], acc[i][j], 0, 0, 0);
        }
    }

    const int ncol = (blockIdx.x & 7) * 128 + wn * 64;   // col base within projection
    const float scale = (sel == 0) ? qscale : 1.0f;
    const float* bias = (sel == 0) ? bq : (sel == 1) ? bk : bv;

    if (sel == 2) {
        // V: transposed per-head write Vt[(b*D+dk)*S+s], packed b64 runs along s
        const int bb_ = m0 >> 11;
        #pragma unroll
        for (int j = 0; j < 4; ++j) {
            const int dk = ncol + j * 16 + l16;
            const float bvv = bias[dk];
            #pragma unroll
            for (int i = 0; i < 4; ++i) {
                const int sb = (m0 & (S_ - 1)) + wm * 64 + i * 16 + quad * 4;
                uint2 w;
                w.x = pk_bf16(acc[i][j][0] + bvv, acc[i][j][1] + bvv);
                w.y = pk_bf16(acc[i][j][2] + bvv, acc[i][j][3] + bvv);
                *(uint2*)(Vt + (size_t)(bb_ * D_ + dk) * S_ + sb) = w;
            }
        }
    } else {
        unsigned short* Outp = sel ? Kw : Qw;
        #pragma unroll
        for (int j = 0; j < 4; ++j) {
            const int n = ncol + j * 16 + l16;
            const float bvv = bias[n];
            #pragma unroll
            for (int i = 0; i < 4; ++i) {
                #pragma unroll
                for (int r = 0; r < 4; ++r) {
                    const int m = m0 + wm * 64 + i * 16 + quad * 4 + r;
                    Outp[(size_t)m * D_ + n] = f2bf((acc[i][j][r] + bvv) * scale);
                }
            }
        }
    }
}

// Output GEMM: C = X * W^T + bias (fp32 out), m97 pattern, 128x128 tile.
__global__ __launch_bounds__(256, 3) void gemm_out(
    const unsigned short* __restrict__ X, const unsigned short* __restrict__ W,
    const float* __restrict__ bias, float* __restrict__ Out)
{
    __shared__ unsigned short As[128 * 64];
    __shared__ unsigned short Bs[128 * 64];

    const int tid  = threadIdx.x;
    const int lane = tid & 63, wave = tid >> 6;
    const int l16  = lane & 15, quad = lane >> 4;
    const int wm = wave & 1, wn = wave >> 1;
    const int n0 = blockIdx.x * 128, m0 = blockIdx.y * 128;
    const int xr = l16 & 7;

    const int row8 = lane >> 3;
    const int sc   = ((lane & 7) ^ row8) * 8;

    f32x4 acc[4][4] = {};

    for (int k0 = 0; k0 < D_; k0 += 64) {
        __syncthreads();
        #pragma unroll
        for (int j = 0; j < 4; ++j) {
            const int ca = wave * 4 + j;
            const int r  = ca * 8 + row8;
            gl2lds16(X + (size_t)(m0 + r) * D_ + k0 + sc, &As[ca * 512 + (lane & 63) * 8]);
            gl2lds16(W + (size_t)(n0 + r) * D_ + k0 + sc, &Bs[ca * 512 + (lane & 63) * 8]);
        }
        __syncthreads();

        #pragma unroll
        for (int s = 0; s < 2; ++s) {
            bf16x8 a[4], bb[4];
            #pragma unroll
            for (int i = 0; i < 4; ++i)
                a[i] = *(const bf16x8*)&As[(wm * 64 + i * 16 + l16) * 64 + (((s * 4 + quad) ^ xr)) * 8];
            #pragma unroll
            for (int j = 0; j < 4; ++j)
                bb[j] = *(const bf16x8*)&Bs[(wn * 64 + j * 16 + l16) * 64 + (((s * 4 + quad) ^ xr)) * 8];
            #pragma unroll
            for (int i = 0; i < 4; ++i)
                #pragma unroll
                for (int j = 0; j < 4; ++j)
                    acc[i][j] = __builtin_amdgcn_mfma_f32_16x16x32_bf16(a[i], bb[j], acc[i][j], 0, 0, 0);
        }
    }

    #pragma unroll
    for (int j = 0; j < 4; ++j) {
        const int n = n0 + wn * 64 + j * 16 + l16;
        const float bv = bias[n];
        #pragma unroll
        for (int i = 0; i < 4; ++i) {
            #pragma unroll
            for (int r = 0; r < 4; ++r) {
                const int m = m0 + wm * 64 + i * 16 + quad * 4 + r;
                Out[(size_t)m * D_ + n] = acc[i][j][r] + bv;
            }
        }
    }
}

// Pack mask (B,S,S int32) into bitmask words: pm[(b*S+q)*(S/64)+w] bit k.
__global__ __launch_bounds__(256) void pack_mask(
    const int* __restrict__ mask, unsigned long long* __restrict__ pm)
{
    const int gid  = blockIdx.x * 256 + threadIdx.x;
    const int w    = gid >> 6;
    const int lane = threadIdx.x & 63;
    const int mv = mask[(size_t)w * 64 + lane];
    const unsigned long long bal = __ballot(mv != 0);
    if (lane == 0) pm[w] = bal;
}

// Flash attention, transposed-score, fixed-max softmax, MFMA row-sums.
// R3: revert R2's global->VGPR K loads (latency disaster: MfmaUtil 10%).
// Geometry change instead: QBLK 64 -> 128 (each wave owns 32 q rows, 2
// q-frags). Ks/Vs LDS reads are shared across both q-frags -> LDS bytes
// per unit of work drop 18KB -> 10KB (-44%); per-tile mask/addressing
// amortizes 2x. QK^T runs in two mb-halves so sct stays at 16 regs.
// LDS 40KB = Ks 8K (single-buf, staged under PV after mid barrier)
// + Vs 2x8K (dbuf, prefetch at tile top) + Ps 16K -> 4 blocks/CU, and
// grid 1024 = exactly one fully-resident round (zero tail).
// XCD-chunked bijective swizzle: each XCD owns 8 complete bh-groups ->
// K/V working set = 4MB = one XCD L2; co-resident q-blocks sweep k-tiles
// in lockstep -> K/V fetched ~once per XCD from HBM.
__global__ __launch_bounds__(256, 4) void attn_kernel(
    const unsigned short* __restrict__ Q,
    const unsigned short* __restrict__ Kg,
    const unsigned short* __restrict__ Vt,
    const unsigned long long* __restrict__ pm,
    unsigned short* __restrict__ O)
{
    __shared__ unsigned short Ks[64 * 64];
    __shared__ unsigned short Vs[2][64 * 64];
    __shared__ unsigned short Ps[128 * 64];

    const int tid  = threadIdx.x;
    const int lane = tid & 63, wave = tid >> 6;
    const int l16  = lane & 15, quad = lane >> 4;

    // XCD-chunked swizzle (bijective: 1024 % 8 == 0). gridDim = (16, 64).
    const int n  = blockIdx.y * 16 + blockIdx.x;
    const int ns = (n & 7) * 128 + (n >> 3);
    const int b  = ns >> 8;
    const int h  = (ns >> 4) & 15;
    const int q0 = (ns & 15) * 128;
    const int xq = l16 & 7;

    // all-ones B operand for the row-sum MFMA
    union { uint4 u; bf16x8 v; } ones_u;
    ones_u.u = make_uint4(0x3F803F80u, 0x3F803F80u, 0x3F803F80u, 0x3F803F80u);
    const bf16x8 vb_ones = ones_u.v;

    // Q fragments: qa[qf][s], wave owns q rows q0 + wave*32 + qf*16 + l16
    bf16x8 qa[2][2];
    #pragma unroll
    for (int qf = 0; qf < 2; ++qf) {
        const unsigned short* qp =
            Q + (size_t)(b * S_ + q0 + wave * 32 + qf * 16 + l16) * D_ + h * DK_ + quad * 8;
        qa[qf][0] = *(const bf16x8*)qp;
        qa[qf][1] = *(const bf16x8*)(qp + 32);
    }

    const unsigned short* Kbase = Kg + (size_t)(b * S_) * D_ + h * DK_;
    const unsigned short* Vbase = Vt + (size_t)(b * D_ + h * DK_) * S_;

    auto stageK = [&](int kt2) {
        const int k0 = kt2 * 64;
        #pragma unroll
        for (int j = 0; j < 2; ++j) {
            const int c = j * 256 + tid;
            const int row = c >> 3;
            const int cl = (c & 7) ^ (row & 7);
            gl2lds16(Kbase + (size_t)(k0 + row) * D_ + cl * 8, &Ks[c * 8]);
        }
    };
    auto stageV = [&](int bi2, int kt2) {
        const int k0 = kt2 * 64;
        #pragma unroll
        for (int j = 0; j < 2; ++j) {
            const int c = j * 256 + tid;
            const int row = c >> 3;
            const int cl = (c & 7) ^ (row & 7);
            gl2lds16(Vbase + (size_t)row * S_ + k0 + cl * 8, &Vs[bi2][c * 8]);
        }
    };

    const unsigned long long* pmq0 =
        pm + (size_t)(b * S_ + q0 + wave * 32 + l16) * (S_ / 64);
    const unsigned long long* pmq1 = pmq0 + (size_t)16 * (S_ / 64);

    f32x4 oacc[2][5] = {};

    stageK(0);
    stageV(0, 0);
    __syncthreads();

    int bi = 0;
    for (int kt = 0; kt < S_ / 64; ++kt) {
        const bool more = (kt + 1 < S_ / 64);
        const unsigned long long wq0 = pmq0[kt];
        const unsigned long long wq1 = pmq1[kt];
        if (more) stageV(bi ^ 1, kt + 1);   // V prefetch overlaps QK^T + softmax

        // QK^T + softmax in two mb-halves (keeps sct at 16 regs).
        #pragma unroll
        for (int half = 0; half < 2; ++half) {
            f32x4 sct[2][2] = {};
            __builtin_amdgcn_s_setprio(1);
            #pragma unroll
            for (int s = 0; s < 2; ++s) {
                const int cs = ((s * 4 + quad) ^ xq) * 8;
                #pragma unroll
                for (int mbh = 0; mbh < 2; ++mbh) {
                    bf16x8 ka = *(const bf16x8*)&Ks[((half * 2 + mbh) * 16 + l16) * 64 + cs];
                    sct[mbh][0] = __builtin_amdgcn_mfma_f32_16x16x32_bf16(ka, qa[0][s], sct[mbh][0], 0, 0, 0);
                    sct[mbh][1] = __builtin_amdgcn_mfma_f32_16x16x32_bf16(ka, qa[1][s], sct[mbh][1], 0, 0, 0);
                }
            }
            __builtin_amdgcn_s_setprio(0);

            #pragma unroll
            for (int qf = 0; qf < 2; ++qf) {
                const unsigned long long wq = qf ? wq1 : wq0;
                #pragma unroll
                for (int mbh = 0; mbh < 2; ++mbh) {
                    const int mb = half * 2 + mbh;
                    const unsigned nib = (unsigned)(wq >> (mb * 16 + quad * 4)) & 0xFu;
                    float e[4];
                    #pragma unroll
                    for (int r = 0; r < 4; ++r) {
                        float x = __builtin_amdgcn_exp2f(sct[mbh][qf][r]);
                        e[r] = ((nib >> r) & 1u) ? x : 0.f;
                    }
                    uint2 w;
                    w.x = pk_bf16(e[0], e[1]);
                    w.y = pk_bf16(e[2], e[3]);
                    *(uint2*)&Ps[(wave * 32 + qf * 16 + l16) * 64 +
                                 ((mb * 16 + quad * 4) ^ (xq * 8))] = w;
                }
            }
        }

        __syncthreads();                 // all waves done reading Ks
        if (more) stageK(kt + 1);        // K staging overlaps PV

        // PV (+ row-sum via constant ones B): A = P rows (q), B = Vs rows (d)
        __builtin_amdgcn_s_setprio(1);
        #pragma unroll
        for (int s = 0; s < 2; ++s) {
            const int cs = ((s * 4 + quad) ^ xq) * 8;
            bf16x8 pa0 = *(const bf16x8*)&Ps[(wave * 32 + l16) * 64 +
                                             ((s * 32 + quad * 8) ^ (xq * 8))];
            bf16x8 pa1 = *(const bf16x8*)&Ps[(wave * 32 + 16 + l16) * 64 +
                                             ((s * 32 + quad * 8) ^ (xq * 8))];
            #pragma unroll
            for (int db = 0; db < 4; ++db) {
                bf16x8 vb = *(const bf16x8*)&Vs[bi][(db * 16 + l16) * 64 + cs];
                oacc[0][db] = __builtin_amdgcn_mfma_f32_16x16x32_bf16(pa0, vb, oacc[0][db], 0, 0, 0);
                oacc[1][db] = __builtin_amdgcn_mfma_f32_16x16x32_bf16(pa1, vb, oacc[1][db], 0, 0, 0);
            }
            oacc[0][4] = __builtin_amdgcn_mfma_f32_16x16x32_bf16(pa0, vb_ones, oacc[0][4], 0, 0, 0);
            oacc[1][4] = __builtin_amdgcn_mfma_f32_16x16x32_bf16(pa1, vb_ones, oacc[1][4], 0, 0, 0);
        }
        __builtin_amdgcn_s_setprio(0);

        __syncthreads();   // drains K+V staging (vmcnt0) + guards Vs swap
        bi ^= 1;
    }

    // epilogue: lane holds rows q = quad*4+r, cols d = db*16+l16; sum in oacc[qf][4][r]
    #pragma unroll
    for (int qf = 0; qf < 2; ++qf) {
        #pragma unroll
        for (int r = 0; r < 4; ++r) {
            const float linv = 1.0f / oacc[qf][4][r];
            const int qg = q0 + wave * 32 + qf * 16 + quad * 4 + r;
            #pragma unroll
            for (int db = 0; db < 4; ++db) {
                O[(size_t)(b * S_ + qg) * D_ + h * DK_ + db * 16 + l16] =
                    f2bf(oacc[qf][db][r] * linv);
            }
        }
    }
}

extern "C" void kernel_launch(void* const* d_in, const int* in_sizes, int n_in,
                              void* d_out, int out_size, void* d_ws, size_t ws_size,
                              hipStream_t stream)
{
    const float* q   = (const float*)d_in[0];
    const float* k   = (const float*)d_in[1];
    const float* v   = (const float*)d_in[2];
    const int* mask  = (const int*)d_in[3];
    const float* Wq  = (const float*)d_in[4];
    const float* bq  = (const float*)d_in[5];
    const float* Wk  = (const float*)d_in[6];
    const float* bk  = (const float*)d_in[7];
    const float* Wv  = (const float*)d_in[8];
    const float* bv  = (const float*)d_in[9];
    const float* Wo  = (const float*)d_in[10];
    const float* bo  = (const float*)d_in[11];

    const size_t MN = (size_t)B_ * S_ * D_;    // 8.4M elements
    const size_t WN = (size_t)D_ * D_;         // 1M elements
    unsigned short* qb  = (unsigned short*)d_ws;   // bf16 activations
    unsigned short* kb  = qb + MN;
    unsigned short* vb  = kb + MN;
    unsigned short* Qw  = vb + MN;
    unsigned short* Kw  = Qw + MN;
    unsigned short* Vt  = Kw + MN;
    unsigned short* wqb = Vt + MN;   // weights: wqb/wkb/wvb CONTIGUOUS = Wqkv
    unsigned short* wkb = wqb + WN;
    unsigned short* wvb = wkb + WN;
    unsigned short* wob = wvb + WN;
    unsigned short* Ow  = qb;   // qb dead after QKV-GEMM; attn writes Ow after
    // Packed mask (2 MB) in d_out scratch; final GEMM overwrites all of d_out.
    unsigned long long* pm = (unsigned long long*)d_out;

    dim3 blk(256);
    const int actBlocks = (int)(MN / 8 / 256);   // 4096
    const int wBlocks   = (int)(WN / 8 / 256);   // 512

    pack_mask<<<(B_ * S_ * S_) / 256, blk, 0, stream>>>(mask, pm);

    cast_act<<<dim3(actBlocks, 3), blk, 0, stream>>>(q, k, v, qb, kb, vb);
    cast_w<<<dim3(wBlocks, 4), blk, 0, stream>>>(Wq, Wk, Wv, Wo, wqb, wkb, wvb, wob);

    // Q scaled by log2(e)/sqrt(DK) -> attention scores already in exp2 domain
    const float qscale = 1.44269504088896341f * 0.125f;

    gemm_qkv<<<dim3(3 * D_ / 128, (B_ * S_) / 128), blk, 0, stream>>>(
        qb, kb, vb, wqb, bq, bk, bv, Qw, Kw, Vt, qscale);

    attn_kernel<<<dim3(S_ / 128, B_ * H_), blk, 0, stream>>>(Qw, Kw, Vt, pm, Ow);

    gemm_out<<<dim3(D_ / 128, (B_ * S_) / 128), blk, 0, stream>>>(
        Ow, wob, bo, (float*)d_out);
}